// Round 1
// baseline (1564.433 us; speedup 1.0000x reference)
//
#include <hip/hip_runtime.h>
#include <math.h>

#define D 64
#define ED 16
#define NEG 0.2f
#define BN_EPS 1e-5f

// ---------------- CSR construction ----------------

__global__ void k_count(const int* __restrict__ dst, int* __restrict__ cnt, int e) {
    int i = blockIdx.x * blockDim.x + threadIdx.x;
    if (i < e) atomicAdd(&cnt[dst[i]], 1);
}

__global__ void k_scan(const int* __restrict__ cnt, int* __restrict__ off, int n) {
    __shared__ int buf[1024];
    __shared__ int carry;
    if (threadIdx.x == 0) { carry = 0; off[0] = 0; }
    __syncthreads();
    for (int base = 0; base < n; base += 1024) {
        int i = base + (int)threadIdx.x;
        int v = (i < n) ? cnt[i] : 0;
        buf[threadIdx.x] = v;
        __syncthreads();
        for (int d = 1; d < 1024; d <<= 1) {
            int t = (threadIdx.x >= (unsigned)d) ? buf[threadIdx.x - d] : 0;
            __syncthreads();
            buf[threadIdx.x] += t;
            __syncthreads();
        }
        if (i < n) off[i + 1] = carry + buf[threadIdx.x];
        __syncthreads();
        if (threadIdx.x == 0) carry += buf[1023];
        __syncthreads();
    }
}

__global__ void k_scatter(const int* __restrict__ src, const int* __restrict__ dst,
                          const int* __restrict__ off, int* __restrict__ fill,
                          int* __restrict__ eid, int* __restrict__ srcs, int e) {
    int i = blockIdx.x * blockDim.x + threadIdx.x;
    if (i < e) {
        int d = dst[i];
        int p = off[d] + atomicAdd(&fill[d], 1);
        eid[p]  = i;
        srcs[p] = src[i];
    }
}

// loop_attr[i] = mean over incoming edges of edge_attr (0 if no in-edges)
__global__ void k_loopattr(const float* __restrict__ ea, const int* __restrict__ eid,
                           const int* __restrict__ off, float* __restrict__ la, int n) {
    int lane = threadIdx.x & 63;
    int wid  = blockIdx.x * (blockDim.x >> 6) + (threadIdx.x >> 6);
    int nw   = gridDim.x * (blockDim.x >> 6);
    for (int i = wid; i < n; i += nw) {
        int beg = off[i], end = off[i + 1];
        if (lane < ED) {
            float s = 0.f;
            for (int p = beg; p < end; ++p) s += ea[(size_t)eid[p] * ED + lane];
            float deg = (float)(end - beg);
            la[(size_t)i * ED + lane] = s / fmaxf(deg, 1.f);
        }
    }
}

// ---------------- per-layer kernels ----------------

// xl = h @ Wl, xr = h @ Wr     (D=64, lane = output column, wave = row)
__global__ void k_gemm(const float* __restrict__ h, const float* __restrict__ Wl,
                       const float* __restrict__ Wr, float* __restrict__ xl,
                       float* __restrict__ xr, int n) {
    __shared__ float wl[D * D];
    __shared__ float wr[D * D];
    for (int i = threadIdx.x; i < D * D; i += blockDim.x) { wl[i] = Wl[i]; wr[i] = Wr[i]; }
    __syncthreads();
    int lane = threadIdx.x & 63;
    int wid  = blockIdx.x * (blockDim.x >> 6) + (threadIdx.x >> 6);
    int nw   = gridDim.x * (blockDim.x >> 6);
    for (int r = wid; r < n; r += nw) {
        float hv = h[(size_t)r * D + lane];
        float al = 0.f, ar = 0.f;
        #pragma unroll
        for (int k = 0; k < D; ++k) {
            float b = __shfl(hv, k, 64);
            al += b * wl[k * D + lane];
            ar += b * wr[k * D + lane];
        }
        xl[(size_t)r * D + lane] = al;
        xr[(size_t)r * D + lane] = ar;
    }
}

// fused GATv2: per-dst-node online softmax + aggregation. wave = node, lane = feature.
__global__ void k_gat(const float* __restrict__ xl, const float* __restrict__ xr,
                      const float* __restrict__ ea, const float* __restrict__ la,
                      const int* __restrict__ eid, const int* __restrict__ srcs,
                      const int* __restrict__ off, const float* __restrict__ We,
                      const float* __restrict__ att, const float* __restrict__ bias,
                      float* __restrict__ out, int n, int do_elu) {
    __shared__ float we[ED * D];
    for (int i = threadIdx.x; i < ED * D; i += blockDim.x) we[i] = We[i];
    __syncthreads();
    int lane = threadIdx.x & 63;
    int wid  = blockIdx.x * (blockDim.x >> 6) + (threadIdx.x >> 6);
    int nw   = gridDim.x * (blockDim.x >> 6);
    float attv = att[lane];
    float bv   = bias[lane];
    for (int i = wid; i < n; i += nw) {
        int beg = off[i], end = off[i + 1];
        float xrv = xr[(size_t)i * D + lane];
        float mmax = -INFINITY, denom = 0.f, acc = 0.f;
        for (int pos = beg; pos <= end; ++pos) {   // pos==end is the self-loop
            int s;
            float eav;
            if (pos < end) {
                int e = eid[pos];
                s = srcs[pos];
                eav = (lane < ED) ? ea[(size_t)e * ED + lane] : 0.f;
            } else {
                s = i;
                eav = (lane < ED) ? la[(size_t)i * ED + lane] : 0.f;
            }
            float xls = xl[(size_t)s * D + lane];
            float eev = 0.f;
            #pragma unroll
            for (int j = 0; j < ED; ++j)
                eev += __shfl(eav, j, 64) * we[j * D + lane];
            float m = xls + xrv + eev;
            float t = (m > 0.f ? m : NEG * m) * attv;
            #pragma unroll
            for (int o = 32; o >= 1; o >>= 1) t += __shfl_xor(t, o, 64);
            if (t > mmax) {
                float sc = expf(mmax - t);
                denom *= sc; acc *= sc; mmax = t;
            }
            float ev = expf(t - mmax);
            denom += ev;
            acc   += ev * xls;
        }
        float o = acc / denom + bv;
        if (do_elu) o = (o > 0.f) ? o : expm1f(o);
        out[(size_t)i * D + lane] = o;
    }
}

// ---------------- batchnorm ----------------

__global__ void k_bnstats(const float* __restrict__ h, float* __restrict__ stat, int n) {
    __shared__ float ssum[D], ssq[D];
    if (threadIdx.x < D) { ssum[threadIdx.x] = 0.f; ssq[threadIdx.x] = 0.f; }
    __syncthreads();
    int lane = threadIdx.x & 63;
    int wid  = blockIdx.x * (blockDim.x >> 6) + (threadIdx.x >> 6);
    int nw   = gridDim.x * (blockDim.x >> 6);
    float s = 0.f, q = 0.f;
    for (int r = wid; r < n; r += nw) {
        float v = h[(size_t)r * D + lane];
        s += v; q += v * v;
    }
    atomicAdd(&ssum[lane], s);
    atomicAdd(&ssq[lane], q);
    __syncthreads();
    if (threadIdx.x < D) {
        atomicAdd(&stat[threadIdx.x], ssum[threadIdx.x]);
        atomicAdd(&stat[D + threadIdx.x], ssq[threadIdx.x]);
    }
}

__global__ void k_bnfinal(float* __restrict__ stat, const float* __restrict__ gamma,
                          const float* __restrict__ beta, int n) {
    int i = threadIdx.x;
    if (i < D) {
        float mean = stat[i] / (float)n;
        float var  = stat[D + i] / (float)n - mean * mean;
        float sc   = gamma[i] * rsqrtf(var + BN_EPS);
        stat[2 * D + i] = sc;
        stat[3 * D + i] = beta[i] - mean * sc;
    }
}

__global__ void k_bnapply(float* __restrict__ h, const float* __restrict__ stat,
                          int n, int elu_after) {
    int idx = blockIdx.x * blockDim.x + threadIdx.x;
    if (idx >= n * D) return;
    int c = idx & (D - 1);
    float v = h[idx] * stat[2 * D + c] + stat[3 * D + c];
    if (elu_after) v = (v > 0.f) ? v : expm1f(v);
    h[idx] = v;
}

// ---------------- launch ----------------

extern "C" void kernel_launch(void* const* d_in, const int* in_sizes, int n_in,
                              void* d_out, int out_size, void* d_ws, size_t ws_size,
                              hipStream_t stream) {
    const float* x     = (const float*)d_in[0];
    const int*   ei    = (const int*)d_in[1];
    const float* ea    = (const float*)d_in[2];
    const float* Wl    = (const float*)d_in[3];
    const float* Wr    = (const float*)d_in[4];
    const float* We    = (const float*)d_in[5];
    const float* att   = (const float*)d_in[6];
    const float* bias  = (const float*)d_in[7];
    const float* gamma = (const float*)d_in[8];
    const float* beta  = (const float*)d_in[9];
    float* out = (float*)d_out;

    int n = in_sizes[0] / D;
    int e = in_sizes[1] / 2;
    const int* src = ei;
    const int* dst = ei + e;

    float* fw   = (float*)d_ws;
    float* xl   = fw;
    float* xr   = xl + (size_t)n * D;
    float* hbuf = xr + (size_t)n * D;
    float* la   = hbuf + (size_t)n * D;
    float* stat = la + (size_t)n * ED;
    int* cnt  = (int*)(stat + 4 * D);
    int* off  = cnt + n;
    int* fill = off + n + 1;
    int* eid  = fill + n;
    int* srcs = eid + e;

    hipMemsetAsync(cnt, 0, (size_t)n * sizeof(int), stream);
    hipMemsetAsync(fill, 0, (size_t)n * sizeof(int), stream);
    k_count<<<(e + 255) / 256, 256, 0, stream>>>(dst, cnt, e);
    k_scan<<<1, 1024, 0, stream>>>(cnt, off, n);
    k_scatter<<<(e + 255) / 256, 256, 0, stream>>>(src, dst, off, fill, eid, srcs, e);
    k_loopattr<<<1024, 256, 0, stream>>>(ea, eid, off, la, n);

    const int gemm_grid = 512;
    const int gat_grid  = (n + 3) / 4;

    // ---- layer 0: conv -> ELU -> BN0 ----
    k_gemm<<<gemm_grid, 256, 0, stream>>>(x, Wl, Wr, xl, xr, n);
    k_gat<<<gat_grid, 256, 0, stream>>>(xl, xr, ea, la, eid, srcs, off,
                                        We, att, bias, hbuf, n, 1);
    hipMemsetAsync(stat, 0, 2 * D * sizeof(float), stream);
    k_bnstats<<<128, 256, 0, stream>>>(hbuf, stat, n);
    k_bnfinal<<<1, 64, 0, stream>>>(stat, gamma, beta, n);
    k_bnapply<<<(n * D + 255) / 256, 256, 0, stream>>>(hbuf, stat, n, 0);

    // ---- layer 1: conv -> BN1 -> ELU ----
    k_gemm<<<gemm_grid, 256, 0, stream>>>(hbuf, Wl + D * D, Wr + D * D, xl, xr, n);
    k_gat<<<gat_grid, 256, 0, stream>>>(xl, xr, ea, la, eid, srcs, off,
                                        We + ED * D, att + D, bias + D, hbuf, n, 0);
    hipMemsetAsync(stat, 0, 2 * D * sizeof(float), stream);
    k_bnstats<<<128, 256, 0, stream>>>(hbuf, stat, n);
    k_bnfinal<<<1, 64, 0, stream>>>(stat, gamma + D, beta + D, n);
    k_bnapply<<<(n * D + 255) / 256, 256, 0, stream>>>(hbuf, stat, n, 1);

    // ---- layer 2: conv only ----
    k_gemm<<<gemm_grid, 256, 0, stream>>>(hbuf, Wl + 2 * D * D, Wr + 2 * D * D, xl, xr, n);
    k_gat<<<gat_grid, 256, 0, stream>>>(xl, xr, ea, la, eid, srcs, off,
                                        We + 2 * ED * D, att + 2 * D, bias + 2 * D, out, n, 0);
}

// Round 2
// 1131.037 us; speedup vs baseline: 1.3832x; 1.3832x over previous
//
#include <hip/hip_runtime.h>
#include <math.h>

#define D 64
#define ED 16
#define NEG 0.2f
#define BN_EPS 1e-5f

// ---------------- CSR construction ----------------

__global__ void k_count(const int* __restrict__ dst, int* __restrict__ cnt, int e) {
    int i = blockIdx.x * blockDim.x + threadIdx.x;
    if (i < e) atomicAdd(&cnt[dst[i]], 1);
}

// block-local inclusive scan of 1024 elems -> off[i+1]; block sums -> bsum
__global__ void k_scan1(const int* __restrict__ cnt, int* __restrict__ off,
                        int* __restrict__ bsum, int n) {
    __shared__ int buf[1024];
    int i = blockIdx.x * 1024 + threadIdx.x;
    int v = (i < n) ? cnt[i] : 0;
    buf[threadIdx.x] = v;
    __syncthreads();
    for (int d = 1; d < 1024; d <<= 1) {
        int t = (threadIdx.x >= (unsigned)d) ? buf[threadIdx.x - d] : 0;
        __syncthreads();
        buf[threadIdx.x] += t;
        __syncthreads();
    }
    if (i < n) off[i + 1] = buf[threadIdx.x];
    if (threadIdx.x == 1023) bsum[blockIdx.x] = buf[1023];
    if (i == 0) off[0] = 0;
}

// exclusive scan of block sums (nb <= 64), single wave
__global__ void k_scan2(int* __restrict__ bsum, int nb) {
    int l = threadIdx.x;
    int v = (l < nb) ? bsum[l] : 0;
    #pragma unroll
    for (int o = 1; o < 64; o <<= 1) {
        int t = __shfl_up(v, o, 64);
        if (l >= o) v += t;
    }
    int ex = __shfl_up(v, 1, 64);
    if (l == 0) ex = 0;
    if (l < nb) bsum[l] = ex;
}

__global__ void k_scan3(int* __restrict__ off, const int* __restrict__ bsum, int n) {
    int i = blockIdx.x * blockDim.x + threadIdx.x;
    if (i < n) off[i + 1] += bsum[i >> 10];
}

__global__ void k_scatter(const int* __restrict__ src, const int* __restrict__ dst,
                          const int* __restrict__ off, int* __restrict__ fill,
                          int* __restrict__ eid, int* __restrict__ srcs, int e) {
    int i = blockIdx.x * blockDim.x + threadIdx.x;
    if (i < e) {
        int d = dst[i];
        int p = off[d] + atomicAdd(&fill[d], 1);
        eid[p]  = i;
        srcs[p] = src[i];
    }
}

// ---------------- per-layer kernels ----------------

// xl = h' @ Wl, xr = h' @ Wr where h' = optional BN(+ELU) transform of h.
// mode: 0 = plain, 1 = BN, 2 = BN+ELU.  W held entirely in VGPRs.
__global__ __launch_bounds__(256) void k_gemm(
        const float* __restrict__ h, const float* __restrict__ Wl,
        const float* __restrict__ Wr, float* __restrict__ xl,
        float* __restrict__ xr, const float* __restrict__ stat, int mode, int n) {
    int lane = threadIdx.x & 63;
    float wl[D], wr[D];
    #pragma unroll
    for (int k = 0; k < D; ++k) { wl[k] = Wl[k * D + lane]; wr[k] = Wr[k * D + lane]; }
    float sc = 1.f, sh = 0.f;
    if (mode) { sc = stat[2 * D + lane]; sh = stat[3 * D + lane]; }
    int wid = blockIdx.x * (blockDim.x >> 6) + (threadIdx.x >> 6);
    int nw  = gridDim.x * (blockDim.x >> 6);
    for (int r0 = wid * 2; r0 < n; r0 += nw * 2) {
        int r1 = r0 + 1;
        float h0 = h[(size_t)r0 * D + lane];
        float h1 = (r1 < n) ? h[(size_t)r1 * D + lane] : 0.f;
        if (mode) {
            h0 = h0 * sc + sh; h1 = h1 * sc + sh;
            if (mode == 2) {
                h0 = (h0 > 0.f) ? h0 : expm1f(h0);
                h1 = (h1 > 0.f) ? h1 : expm1f(h1);
            }
        }
        float a0 = 0.f, b0 = 0.f, a1 = 0.f, b1 = 0.f;
        #pragma unroll
        for (int k = 0; k < D; ++k) {
            float x0 = __shfl(h0, k, 64);
            float x1 = __shfl(h1, k, 64);
            a0 += x0 * wl[k]; b0 += x0 * wr[k];
            a1 += x1 * wl[k]; b1 += x1 * wr[k];
        }
        xl[(size_t)r0 * D + lane] = a0; xr[(size_t)r0 * D + lane] = b0;
        if (r1 < n) { xl[(size_t)r1 * D + lane] = a1; xr[(size_t)r1 * D + lane] = b1; }
    }
}

// fused GATv2: wave = node, lane = feature; 4 edges per iteration (independent
// butterflies for ILP). Self-loop edge-embedding = eevsum/deg (linearity of @We).
__global__ __launch_bounds__(256) void k_gat(
        const float* __restrict__ xl, const float* __restrict__ xr,
        const float* __restrict__ ea, const int* __restrict__ eid,
        const int* __restrict__ srcs, const int* __restrict__ off,
        const float* __restrict__ We, const float* __restrict__ att,
        const float* __restrict__ bias, float* __restrict__ out, int n, int do_elu) {
    int lane = threadIdx.x & 63;
    float weR[ED];
    #pragma unroll
    for (int j = 0; j < ED; ++j) weR[j] = We[j * D + lane];
    float attv = att[lane], bv = bias[lane];
    int g = lane >> 4;          // lane-group = edge slot within a 4-edge pack
    int c16 = lane & 15;
    int wid = blockIdx.x * (blockDim.x >> 6) + (threadIdx.x >> 6);
    int nw  = gridDim.x * (blockDim.x >> 6);
    for (int i = wid; i < n; i += nw) {
        int beg = off[i], end = off[i + 1];
        float xrv = xr[(size_t)i * D + lane];
        float mmax = -INFINITY, denom = 0.f, acc = 0.f, eevsum = 0.f;
        for (int pos = beg; pos < end; pos += 4) {
            int rem = end - pos;                  // >= 1
            // one gather: lane-group u loads edge (pos+u)'s attr column (lane&15)
            int er = eid[pos + ((g < rem) ? g : 0)];
            float eab = (g < rem) ? ea[(size_t)er * ED + c16] : 0.f;
            int s[4]; float xls[4], t[4];
            #pragma unroll
            for (int u = 0; u < 4; ++u) s[u] = (u < rem) ? srcs[pos + u] : i;
            #pragma unroll
            for (int u = 0; u < 4; ++u) xls[u] = xl[(size_t)s[u] * D + lane];
            #pragma unroll
            for (int u = 0; u < 4; ++u) {
                float eev = 0.f;
                #pragma unroll
                for (int j = 0; j < ED; ++j)
                    eev += __shfl(eab, u * 16 + j, 64) * weR[j];
                eevsum += (u < rem) ? eev : 0.f;
                float m = xls[u] + xrv + eev;
                t[u] = (m > 0.f ? m : NEG * m) * attv;
            }
            #pragma unroll
            for (int o = 32; o >= 1; o >>= 1) {   // 4 independent butterflies
                t[0] += __shfl_xor(t[0], o, 64);
                t[1] += __shfl_xor(t[1], o, 64);
                t[2] += __shfl_xor(t[2], o, 64);
                t[3] += __shfl_xor(t[3], o, 64);
            }
            #pragma unroll
            for (int u = 0; u < 4; ++u) if (u >= rem) t[u] = -INFINITY;
            float gmax = fmaxf(fmaxf(t[0], t[1]), fmaxf(t[2], t[3]));
            float nmax = fmaxf(mmax, gmax);
            float scal = __expf(mmax - nmax);     // first iter: exp(-inf)=0, denom/acc are 0
            denom *= scal; acc *= scal; mmax = nmax;
            #pragma unroll
            for (int u = 0; u < 4; ++u) {
                float ev = __expf(t[u] - mmax);   // inactive: exp(-inf)=0
                denom += ev;
                acc   += ev * xls[u];
            }
        }
        // self-loop: loop_attr@We == mean of incoming eev (linearity); 0 if deg==0
        {
            int deg = end - beg;
            float eev = (deg > 0) ? eevsum / (float)deg : 0.f;
            float xli = xl[(size_t)i * D + lane];
            float m = xli + xrv + eev;
            float t0 = (m > 0.f ? m : NEG * m) * attv;
            #pragma unroll
            for (int o = 32; o >= 1; o >>= 1) t0 += __shfl_xor(t0, o, 64);
            float nmax = fmaxf(mmax, t0);
            float scal = __expf(mmax - nmax);
            denom *= scal; acc *= scal;
            float ev = __expf(t0 - nmax);
            denom += ev; acc += ev * xli;
        }
        float o = acc / denom + bv;
        if (do_elu) o = (o > 0.f) ? o : expm1f(o);
        out[(size_t)i * D + lane] = o;
    }
}

// ---------------- batchnorm stats ----------------

__global__ void k_bnstats(const float* __restrict__ h, float* __restrict__ stat, int n) {
    __shared__ float ssum[D], ssq[D];
    if (threadIdx.x < D) { ssum[threadIdx.x] = 0.f; ssq[threadIdx.x] = 0.f; }
    __syncthreads();
    int lane = threadIdx.x & 63;
    int wid  = blockIdx.x * (blockDim.x >> 6) + (threadIdx.x >> 6);
    int nw   = gridDim.x * (blockDim.x >> 6);
    float s = 0.f, q = 0.f;
    for (int r = wid; r < n; r += nw) {
        float v = h[(size_t)r * D + lane];
        s += v; q += v * v;
    }
    atomicAdd(&ssum[lane], s);
    atomicAdd(&ssq[lane], q);
    __syncthreads();
    if (threadIdx.x < D) {
        atomicAdd(&stat[threadIdx.x], ssum[threadIdx.x]);
        atomicAdd(&stat[D + threadIdx.x], ssq[threadIdx.x]);
    }
}

__global__ void k_bnfinal(float* __restrict__ stat, const float* __restrict__ gamma,
                          const float* __restrict__ beta, int n) {
    int i = threadIdx.x;
    if (i < D) {
        float mean = stat[i] / (float)n;
        float var  = stat[D + i] / (float)n - mean * mean;
        float sc   = gamma[i] * rsqrtf(var + BN_EPS);
        stat[2 * D + i] = sc;
        stat[3 * D + i] = beta[i] - mean * sc;
    }
}

// ---------------- launch ----------------

extern "C" void kernel_launch(void* const* d_in, const int* in_sizes, int n_in,
                              void* d_out, int out_size, void* d_ws, size_t ws_size,
                              hipStream_t stream) {
    const float* x     = (const float*)d_in[0];
    const int*   ei    = (const int*)d_in[1];
    const float* ea    = (const float*)d_in[2];
    const float* Wl    = (const float*)d_in[3];
    const float* Wr    = (const float*)d_in[4];
    const float* We    = (const float*)d_in[5];
    const float* att   = (const float*)d_in[6];
    const float* bias  = (const float*)d_in[7];
    const float* gamma = (const float*)d_in[8];
    const float* beta  = (const float*)d_in[9];
    float* out = (float*)d_out;

    int n = in_sizes[0] / D;
    int e = in_sizes[1] / 2;
    const int* src = ei;
    const int* dst = ei + e;
    int nb = (n + 1023) / 1024;

    float* xl   = (float*)d_ws;
    float* xr   = xl + (size_t)n * D;
    float* hbuf = xr + (size_t)n * D;
    float* stat = hbuf + (size_t)n * D;
    int* cnt  = (int*)(stat + 4 * D);
    int* off  = cnt + n;
    int* fill = off + n + 1;
    int* bsum = fill + n;
    int* eid  = bsum + 256;
    int* srcs = eid + e;

    hipMemsetAsync(cnt, 0, (size_t)n * sizeof(int), stream);
    hipMemsetAsync(fill, 0, (size_t)n * sizeof(int), stream);
    k_count<<<(e + 255) / 256, 256, 0, stream>>>(dst, cnt, e);
    k_scan1<<<nb, 1024, 0, stream>>>(cnt, off, bsum, n);
    k_scan2<<<1, 64, 0, stream>>>(bsum, nb);
    k_scan3<<<(n + 255) / 256, 256, 0, stream>>>(off, bsum, n);
    k_scatter<<<(e + 255) / 256, 256, 0, stream>>>(src, dst, off, fill, eid, srcs, e);

    const int gemm_grid = 512;
    const int gat_grid  = 2048;

    // ---- layer 0: conv -> ELU (in gat) -> BN0 stats (apply folded into gemm1) ----
    k_gemm<<<gemm_grid, 256, 0, stream>>>(x, Wl, Wr, xl, xr, stat, 0, n);
    k_gat<<<gat_grid, 256, 0, stream>>>(xl, xr, ea, eid, srcs, off,
                                        We, att, bias, hbuf, n, 1);
    hipMemsetAsync(stat, 0, 2 * D * sizeof(float), stream);
    k_bnstats<<<256, 256, 0, stream>>>(hbuf, stat, n);
    k_bnfinal<<<1, 64, 0, stream>>>(stat, gamma, beta, n);

    // ---- layer 1: conv (BN0 folded) -> BN1 stats -> (BN1+ELU folded into gemm2) ----
    k_gemm<<<gemm_grid, 256, 0, stream>>>(hbuf, Wl + D * D, Wr + D * D, xl, xr, stat, 1, n);
    k_gat<<<gat_grid, 256, 0, stream>>>(xl, xr, ea, eid, srcs, off,
                                        We + ED * D, att + D, bias + D, hbuf, n, 0);
    hipMemsetAsync(stat, 0, 2 * D * sizeof(float), stream);
    k_bnstats<<<256, 256, 0, stream>>>(hbuf, stat, n);
    k_bnfinal<<<1, 64, 0, stream>>>(stat, gamma + D, beta + D, n);

    // ---- layer 2: conv (BN1+ELU folded) -> out ----
    k_gemm<<<gemm_grid, 256, 0, stream>>>(hbuf, Wl + 2 * D * D, Wr + 2 * D * D, xl, xr, stat, 2, n);
    k_gat<<<gat_grid, 256, 0, stream>>>(xl, xr, ea, eid, srcs, off,
                                        We + 2 * ED * D, att + 2 * D, bias + 2 * D, out, n, 0);
}

// Round 3
// 872.848 us; speedup vs baseline: 1.7923x; 1.2958x over previous
//
#include <hip/hip_runtime.h>
#include <math.h>

#define D 64
#define ED 16
#define NEG 0.2f
#define BN_EPS 1e-5f
#define NINF (-INFINITY)

// ---------------- CSR construction ----------------

__global__ void k_count(const int* __restrict__ dst, int* __restrict__ cnt,
                        float* __restrict__ stat, int e) {
    int i = blockIdx.x * blockDim.x + threadIdx.x;
    if (blockIdx.x == 0 && threadIdx.x < 256) stat[threadIdx.x] = 0.f;  // zero BN stat bufs
    if (i < e) atomicAdd(&cnt[dst[i]], 1);
}

__global__ void k_scan1(const int* __restrict__ cnt, int* __restrict__ off,
                        int* __restrict__ bsum, int n) {
    __shared__ int buf[1024];
    int i = blockIdx.x * 1024 + threadIdx.x;
    int v = (i < n) ? cnt[i] : 0;
    buf[threadIdx.x] = v;
    __syncthreads();
    for (int d = 1; d < 1024; d <<= 1) {
        int t = (threadIdx.x >= (unsigned)d) ? buf[threadIdx.x - d] : 0;
        __syncthreads();
        buf[threadIdx.x] += t;
        __syncthreads();
    }
    if (i < n) off[i + 1] = buf[threadIdx.x];
    if (threadIdx.x == 1023) bsum[blockIdx.x] = buf[1023];
    if (i == 0) off[0] = 0;
}

__global__ void k_scan2(int* __restrict__ bsum, int nb) {
    int l = threadIdx.x;
    int v = (l < nb) ? bsum[l] : 0;
    #pragma unroll
    for (int o = 1; o < 64; o <<= 1) {
        int t = __shfl_up(v, o, 64);
        if (l >= o) v += t;
    }
    int ex = __shfl_up(v, 1, 64);
    if (l == 0) ex = 0;
    if (l < nb) bsum[l] = ex;
}

__global__ void k_scan3(int* __restrict__ off, const int* __restrict__ bsum, int n) {
    int i = blockIdx.x * blockDim.x + threadIdx.x;
    if (i < n) off[i + 1] += bsum[i >> 10];
}

__global__ void k_scatter(const int* __restrict__ src, const int* __restrict__ dst,
                          const int* __restrict__ off, int* __restrict__ fill,
                          int* __restrict__ eid, int* __restrict__ srcs, int e) {
    int i = blockIdx.x * blockDim.x + threadIdx.x;
    if (i < e) {
        int d = dst[i];
        int p = off[d] + atomicAdd(&fill[d], 1);
        eid[p]  = i;
        srcs[p] = src[i];
    }
}

// ---------------- gemm: xl/xr = BN'(h) @ {Wl,Wr}; BN finalize folded in ----------------
// mode: 0 = plain, 1 = BN, 2 = BN+ELU. stat points at this layer's raw {sum[64],sq[64]}.

__global__ __launch_bounds__(256) void k_gemm(
        const float* __restrict__ h, const float* __restrict__ Wl,
        const float* __restrict__ Wr, float* __restrict__ xl,
        float* __restrict__ xr, const float* __restrict__ stat,
        const float* __restrict__ gamma, const float* __restrict__ beta,
        int mode, int n) {
    int lane = threadIdx.x & 63;
    float wl[D], wr[D];
    #pragma unroll
    for (int k = 0; k < D; ++k) { wl[k] = Wl[k * D + lane]; wr[k] = Wr[k * D + lane]; }
    float sc = 1.f, sh = 0.f;
    if (mode) {
        float s = stat[lane], q = stat[64 + lane];
        float mean = s / (float)n;
        float var  = q / (float)n - mean * mean;
        sc = gamma[lane] * rsqrtf(var + BN_EPS);
        sh = beta[lane] - mean * sc;
    }
    int wid = blockIdx.x * (blockDim.x >> 6) + (threadIdx.x >> 6);
    int nw  = gridDim.x * (blockDim.x >> 6);
    for (int r0 = wid * 2; r0 < n; r0 += nw * 2) {
        int r1 = r0 + 1;
        float h0 = h[(size_t)r0 * D + lane];
        float h1 = (r1 < n) ? h[(size_t)r1 * D + lane] : 0.f;
        if (mode) {
            h0 = h0 * sc + sh; h1 = h1 * sc + sh;
            if (mode == 2) {
                h0 = (h0 > 0.f) ? h0 : expm1f(h0);
                h1 = (h1 > 0.f) ? h1 : expm1f(h1);
            }
        }
        float a0 = 0.f, b0 = 0.f, a1 = 0.f, b1 = 0.f;
        #pragma unroll
        for (int k = 0; k < D; ++k) {
            float x0 = __shfl(h0, k, 64);
            float x1 = __shfl(h1, k, 64);
            a0 += x0 * wl[k]; b0 += x0 * wr[k];
            a1 += x1 * wl[k]; b1 += x1 * wr[k];
        }
        xl[(size_t)r0 * D + lane] = a0; xr[(size_t)r0 * D + lane] = b0;
        if (r1 < n) { xl[(size_t)r1 * D + lane] = a1; xr[(size_t)r1 * D + lane] = b1; }
    }
}

// ---------------- fused GATv2 ----------------
// wave = node; 16-lane group g = edge slot (4 edges in flight); lane owns 4 features.
// Per-group online softmax, merged across groups per node. Self-loop edge-embedding
// = mean of incoming ee (linearity of @We). BN stats accumulated in epilogue.

__global__ __launch_bounds__(256) void k_gat(
        const float4* __restrict__ xl4, const float4* __restrict__ xr4,
        const float* __restrict__ ea, const int* __restrict__ eid,
        const int* __restrict__ srcs, const int* __restrict__ off,
        const float4* __restrict__ We4, const float4* __restrict__ att4,
        const float4* __restrict__ bias4, float* __restrict__ out,
        float* __restrict__ stat, int n, int do_elu) {
    __shared__ float ls[128];
    if (threadIdx.x < 128) ls[threadIdx.x] = 0.f;
    __syncthreads();
    int lane = threadIdx.x & 63;
    int g = lane >> 4, c16 = lane & 15, base = g << 4;
    float4 we[ED];
    #pragma unroll
    for (int j = 0; j < ED; ++j) we[j] = We4[j * 16 + c16];
    float4 av = att4[c16];
    int wid = blockIdx.x * (blockDim.x >> 6) + (threadIdx.x >> 6);
    int nw  = gridDim.x * (blockDim.x >> 6);
    float bsx = 0.f, bsy = 0.f, bsz = 0.f, bsw = 0.f;
    float bqx = 0.f, bqy = 0.f, bqz = 0.f, bqw = 0.f;
    for (int i = wid; i < n; i += nw) {
        int beg = off[i], end = off[i + 1];
        float4 xrv = xr4[(size_t)i * 16 + c16];
        float mmax = NINF, denom = 0.f;
        float ax = 0.f, ay = 0.f, az = 0.f, aw = 0.f;
        float ex = 0.f, ey = 0.f, ez = 0.f, ew = 0.f;
        for (int pos = beg; pos < end; pos += 4) {
            int rem = end - pos;
            int act = (g < rem);
            float mk = act ? 1.f : 0.f;
            int p = pos + (act ? g : 0);
            int e = eid[p];
            int s = srcs[p];
            float eab = ea[(size_t)e * ED + c16];
            float4 xls = xl4[(size_t)s * 16 + c16];
            float eex = 0.f, eey = 0.f, eez = 0.f, eew = 0.f;
            #pragma unroll
            for (int j = 0; j < ED; ++j) {
                float b = __shfl(eab, base + j, 64);
                eex += b * we[j].x; eey += b * we[j].y;
                eez += b * we[j].z; eew += b * we[j].w;
            }
            ex += mk * eex; ey += mk * eey; ez += mk * eez; ew += mk * eew;
            float mx = xls.x + xrv.x + eex;
            float my = xls.y + xrv.y + eey;
            float mz = xls.z + xrv.z + eez;
            float mw = xls.w + xrv.w + eew;
            float p0 = (mx > 0.f ? mx : NEG * mx) * av.x
                     + (my > 0.f ? my : NEG * my) * av.y
                     + (mz > 0.f ? mz : NEG * mz) * av.z
                     + (mw > 0.f ? mw : NEG * mw) * av.w;
            #pragma unroll
            for (int o = 1; o <= 8; o <<= 1) p0 += __shfl_xor(p0, o, 64);
            float t = act ? p0 : NINF;
            float nm = fmaxf(mmax, t);
            float scal = (mmax == NINF) ? 0.f : __expf(mmax - nm);
            float ev = act ? __expf(t - nm) : 0.f;
            denom = denom * scal + ev;
            ax = ax * scal + ev * xls.x;
            ay = ay * scal + ev * xls.y;
            az = az * scal + ev * xls.z;
            aw = aw * scal + ev * xls.w;
            mmax = nm;
        }
        // merge 4 per-group partial (m, l, acc, eevsum)
        #pragma unroll
        for (int o = 16; o <= 32; o <<= 1) {
            float om = __shfl_xor(mmax, o, 64);
            float od = __shfl_xor(denom, o, 64);
            float oax = __shfl_xor(ax, o, 64);
            float oay = __shfl_xor(ay, o, 64);
            float oaz = __shfl_xor(az, o, 64);
            float oaw = __shfl_xor(aw, o, 64);
            float oex = __shfl_xor(ex, o, 64);
            float oey = __shfl_xor(ey, o, 64);
            float oez = __shfl_xor(ez, o, 64);
            float oew = __shfl_xor(ew, o, 64);
            float nm = fmaxf(mmax, om);
            float s1 = (mmax == NINF) ? 0.f : __expf(mmax - nm);
            float s2 = (om == NINF) ? 0.f : __expf(om - nm);
            denom = denom * s1 + od * s2;
            ax = ax * s1 + oax * s2; ay = ay * s1 + oay * s2;
            az = az * s1 + oaz * s2; aw = aw * s1 + oaw * s2;
            ex += oex; ey += oey; ez += oez; ew += oew;
            mmax = nm;
        }
        // self-loop
        int deg = end - beg;
        float inv = (deg > 0) ? 1.f / (float)deg : 0.f;
        float4 xli = xl4[(size_t)i * 16 + c16];
        float mx = xli.x + xrv.x + ex * inv;
        float my = xli.y + xrv.y + ey * inv;
        float mz = xli.z + xrv.z + ez * inv;
        float mw = xli.w + xrv.w + ew * inv;
        float p0 = (mx > 0.f ? mx : NEG * mx) * av.x
                 + (my > 0.f ? my : NEG * my) * av.y
                 + (mz > 0.f ? mz : NEG * mz) * av.z
                 + (mw > 0.f ? mw : NEG * mw) * av.w;
        #pragma unroll
        for (int o = 1; o <= 8; o <<= 1) p0 += __shfl_xor(p0, o, 64);
        float nm = fmaxf(mmax, p0);
        float scal = (mmax == NINF) ? 0.f : __expf(mmax - nm);
        float ev = __expf(p0 - nm);
        denom = denom * scal + ev;
        ax = ax * scal + ev * xli.x;
        ay = ay * scal + ev * xli.y;
        az = az * scal + ev * xli.z;
        aw = aw * scal + ev * xli.w;
        float invd = 1.f / denom;
        float4 b4 = bias4[c16];
        float ox = ax * invd + b4.x;
        float oy = ay * invd + b4.y;
        float oz = az * invd + b4.z;
        float ow = aw * invd + b4.w;
        if (do_elu) {
            ox = (ox > 0.f) ? ox : expm1f(ox);
            oy = (oy > 0.f) ? oy : expm1f(oy);
            oz = (oz > 0.f) ? oz : expm1f(oz);
            ow = (ow > 0.f) ? ow : expm1f(ow);
        }
        if (g == 0) {
            float4 o4; o4.x = ox; o4.y = oy; o4.z = oz; o4.w = ow;
            ((float4*)out)[(size_t)i * 16 + c16] = o4;
            if (stat) {
                bsx += ox; bsy += oy; bsz += oz; bsw += ow;
                bqx += ox * ox; bqy += oy * oy; bqz += oz * oz; bqw += ow * ow;
            }
        }
    }
    if (stat) {
        if (g == 0) {
            atomicAdd(&ls[c16 * 4 + 0], bsx);
            atomicAdd(&ls[c16 * 4 + 1], bsy);
            atomicAdd(&ls[c16 * 4 + 2], bsz);
            atomicAdd(&ls[c16 * 4 + 3], bsw);
            atomicAdd(&ls[64 + c16 * 4 + 0], bqx);
            atomicAdd(&ls[64 + c16 * 4 + 1], bqy);
            atomicAdd(&ls[64 + c16 * 4 + 2], bqz);
            atomicAdd(&ls[64 + c16 * 4 + 3], bqw);
        }
        __syncthreads();
        if (threadIdx.x < 128) atomicAdd(&stat[threadIdx.x], ls[threadIdx.x]);
    }
}

// ---------------- launch ----------------

extern "C" void kernel_launch(void* const* d_in, const int* in_sizes, int n_in,
                              void* d_out, int out_size, void* d_ws, size_t ws_size,
                              hipStream_t stream) {
    const float* x     = (const float*)d_in[0];
    const int*   ei    = (const int*)d_in[1];
    const float* ea    = (const float*)d_in[2];
    const float* Wl    = (const float*)d_in[3];
    const float* Wr    = (const float*)d_in[4];
    const float* We    = (const float*)d_in[5];
    const float* att   = (const float*)d_in[6];
    const float* bias  = (const float*)d_in[7];
    const float* gamma = (const float*)d_in[8];
    const float* beta  = (const float*)d_in[9];
    float* out = (float*)d_out;

    int n = in_sizes[0] / D;
    int e = in_sizes[1] / 2;
    const int* src = ei;
    const int* dst = ei + e;
    int nb = (n + 1023) / 1024;

    float* xl   = (float*)d_ws;
    float* xr   = xl + (size_t)n * D;
    float* hbuf = xr + (size_t)n * D;
    float* stat = hbuf + (size_t)n * D;        // [2][128]: raw {sum,sq} per BN
    int* cnt  = (int*)(stat + 256);
    int* fill = cnt + n;                       // adjacent to cnt: one memset
    int* off  = fill + n;
    int* bsum = off + n + 1;
    int* eid  = bsum + 256;
    int* srcs = eid + e;

    hipMemsetAsync(cnt, 0, (size_t)(2 * n) * sizeof(int), stream);
    k_count<<<(e + 255) / 256, 256, 0, stream>>>(dst, cnt, stat, e);
    k_scan1<<<nb, 1024, 0, stream>>>(cnt, off, bsum, n);
    k_scan2<<<1, 64, 0, stream>>>(bsum, nb);
    k_scan3<<<(n + 255) / 256, 256, 0, stream>>>(off, bsum, n);
    k_scatter<<<(e + 255) / 256, 256, 0, stream>>>(src, dst, off, fill, eid, srcs, e);

    const int gemm_grid = 512;
    const int gat_grid  = 2048;

    // layer 0: conv -> ELU (in gat) -> BN0 stats (epilogue); BN0 apply folded into gemm1
    k_gemm<<<gemm_grid, 256, 0, stream>>>(x, Wl, Wr, xl, xr, stat, gamma, beta, 0, n);
    k_gat<<<gat_grid, 256, 0, stream>>>((const float4*)xl, (const float4*)xr, ea, eid, srcs, off,
                                        (const float4*)We, (const float4*)att,
                                        (const float4*)bias, hbuf, stat, n, 1);
    // layer 1: conv (BN0 folded) -> BN1 stats (epilogue); BN1+ELU folded into gemm2
    k_gemm<<<gemm_grid, 256, 0, stream>>>(hbuf, Wl + D * D, Wr + D * D, xl, xr,
                                          stat, gamma, beta, 1, n);
    k_gat<<<gat_grid, 256, 0, stream>>>((const float4*)xl, (const float4*)xr, ea, eid, srcs, off,
                                        (const float4*)(We + ED * D), (const float4*)(att + D),
                                        (const float4*)(bias + D), hbuf, stat + 128, n, 0);
    // layer 2: conv (BN1+ELU folded) -> out
    k_gemm<<<gemm_grid, 256, 0, stream>>>(hbuf, Wl + 2 * D * D, Wr + 2 * D * D, xl, xr,
                                          stat + 128, gamma + D, beta + D, 2, n);
    k_gat<<<gat_grid, 256, 0, stream>>>((const float4*)xl, (const float4*)xr, ea, eid, srcs, off,
                                        (const float4*)(We + 2 * ED * D), (const float4*)(att + 2 * D),
                                        (const float4*)(bias + 2 * D), out, (float*)nullptr, n, 0);
}

// Round 4
// 750.869 us; speedup vs baseline: 2.0835x; 1.1624x over previous
//
#include <hip/hip_runtime.h>
#include <math.h>

#define D 64
#define ED 16
#define NEG 0.2f
#define BN_EPS 1e-5f
#define NINF (-INFINITY)

// ---------------- CSR construction ----------------

__global__ void k_count(const int* __restrict__ dst, int* __restrict__ cnt,
                        float* __restrict__ stat, int e) {
    int i = blockIdx.x * blockDim.x + threadIdx.x;
    if (blockIdx.x == 0 && threadIdx.x < 256) stat[threadIdx.x] = 0.f;  // zero BN stat bufs
    if (i < e) atomicAdd(&cnt[dst[i]], 1);
}

__global__ void k_scan1(const int* __restrict__ cnt, int* __restrict__ off,
                        int* __restrict__ bsum, int n) {
    __shared__ int buf[1024];
    int i = blockIdx.x * 1024 + threadIdx.x;
    int v = (i < n) ? cnt[i] : 0;
    buf[threadIdx.x] = v;
    __syncthreads();
    for (int d = 1; d < 1024; d <<= 1) {
        int t = (threadIdx.x >= (unsigned)d) ? buf[threadIdx.x - d] : 0;
        __syncthreads();
        buf[threadIdx.x] += t;
        __syncthreads();
    }
    if (i < n) off[i + 1] = buf[threadIdx.x];
    if (threadIdx.x == 1023) bsum[blockIdx.x] = buf[1023];
    if (i == 0) off[0] = 0;
}

__global__ void k_scan2(int* __restrict__ bsum, int nb) {
    int l = threadIdx.x;
    int v = (l < nb) ? bsum[l] : 0;
    #pragma unroll
    for (int o = 1; o < 64; o <<= 1) {
        int t = __shfl_up(v, o, 64);
        if (l >= o) v += t;
    }
    int ex = __shfl_up(v, 1, 64);
    if (l == 0) ex = 0;
    if (l < nb) bsum[l] = ex;
}

__global__ void k_scan3(int* __restrict__ off, const int* __restrict__ bsum, int n) {
    int i = blockIdx.x * blockDim.x + threadIdx.x;
    if (i < n) off[i + 1] += bsum[i >> 10];
}

// scatter src index AND edge_attr row into CSR (dst-sorted) order
__global__ void k_scatter(const int* __restrict__ src, const int* __restrict__ dst,
                          const int* __restrict__ off, int* __restrict__ fill,
                          int* __restrict__ srcs, float4* __restrict__ eas4,
                          const float4* __restrict__ ea4, int e) {
    int i = blockIdx.x * blockDim.x + threadIdx.x;
    if (i < e) {
        int d = dst[i];
        int p = off[d] + atomicAdd(&fill[d], 1);
        srcs[p] = src[i];
        size_t qi = 4 * (size_t)i, qp = 4 * (size_t)p;
        float4 a0 = ea4[qi], a1 = ea4[qi + 1], a2 = ea4[qi + 2], a3 = ea4[qi + 3];
        eas4[qp] = a0; eas4[qp + 1] = a1; eas4[qp + 2] = a2; eas4[qp + 3] = a3;
    }
}

// ---------------- gemm: xl/xr = BN'(h) @ {Wl,Wr}; BN finalize folded in ----------------
// mode: 0 = plain, 1 = BN, 2 = BN+ELU. stat points at this layer's raw {sum[64],sq[64]}.

__global__ __launch_bounds__(256) void k_gemm(
        const float* __restrict__ h, const float* __restrict__ Wl,
        const float* __restrict__ Wr, float* __restrict__ xl,
        float* __restrict__ xr, const float* __restrict__ stat,
        const float* __restrict__ gamma, const float* __restrict__ beta,
        int mode, int n) {
    int lane = threadIdx.x & 63;
    float wl[D], wr[D];
    #pragma unroll
    for (int k = 0; k < D; ++k) { wl[k] = Wl[k * D + lane]; wr[k] = Wr[k * D + lane]; }
    float sc = 1.f, sh = 0.f;
    if (mode) {
        float s = stat[lane], q = stat[64 + lane];
        float mean = s / (float)n;
        float var  = q / (float)n - mean * mean;
        sc = gamma[lane] * rsqrtf(var + BN_EPS);
        sh = beta[lane] - mean * sc;
    }
    int wid = blockIdx.x * (blockDim.x >> 6) + (threadIdx.x >> 6);
    int nw  = gridDim.x * (blockDim.x >> 6);
    for (int r0 = wid * 2; r0 < n; r0 += nw * 2) {
        int r1 = r0 + 1;
        float h0 = h[(size_t)r0 * D + lane];
        float h1 = (r1 < n) ? h[(size_t)r1 * D + lane] : 0.f;
        if (mode) {
            h0 = h0 * sc + sh; h1 = h1 * sc + sh;
            if (mode == 2) {
                h0 = (h0 > 0.f) ? h0 : expm1f(h0);
                h1 = (h1 > 0.f) ? h1 : expm1f(h1);
            }
        }
        float a0 = 0.f, b0 = 0.f, a1 = 0.f, b1 = 0.f;
        #pragma unroll
        for (int k = 0; k < D; ++k) {
            float x0 = __shfl(h0, k, 64);
            float x1 = __shfl(h1, k, 64);
            a0 += x0 * wl[k]; b0 += x0 * wr[k];
            a1 += x1 * wl[k]; b1 += x1 * wr[k];
        }
        xl[(size_t)r0 * D + lane] = a0; xr[(size_t)r0 * D + lane] = b0;
        if (r1 < n) { xl[(size_t)r1 * D + lane] = a1; xr[(size_t)r1 * D + lane] = b1; }
    }
}

// ---------------- fused GATv2 ----------------
// wave = node; 16-lane group g = edge slot (4 edges/pack); lane owns 4 features.
// eas is pre-sorted edge_attr (CSR order): induction-indexed loads, no indirection.
// eev computed per-lane with pure FMAs (no broadcast shuffles). Software pipeline:
// next pack's srcs+ea issue at top, xl gather mid-iteration.

#define EEV(c) (e0.x*we[0].c + e0.y*we[1].c + e0.z*we[2].c + e0.w*we[3].c \
              + e1.x*we[4].c + e1.y*we[5].c + e1.z*we[6].c + e1.w*we[7].c \
              + e2.x*we[8].c + e2.y*we[9].c + e2.z*we[10].c + e2.w*we[11].c \
              + e3.x*we[12].c + e3.y*we[13].c + e3.z*we[14].c + e3.w*we[15].c)

__global__ __launch_bounds__(256) void k_gat(
        const float4* __restrict__ xl4, const float4* __restrict__ xr4,
        const float4* __restrict__ eas4, const int* __restrict__ srcs,
        const int* __restrict__ off,
        const float4* __restrict__ We4, const float4* __restrict__ att4,
        const float4* __restrict__ bias4, float* __restrict__ out,
        float* __restrict__ stat, int n, int do_elu) {
    __shared__ float ls[128];
    if (threadIdx.x < 128) ls[threadIdx.x] = 0.f;
    __syncthreads();
    int lane = threadIdx.x & 63;
    int g = lane >> 4, c16 = lane & 15;
    float4 we[ED];
    #pragma unroll
    for (int j = 0; j < ED; ++j) we[j] = We4[j * 16 + c16];
    float4 av = att4[c16];
    int wid = blockIdx.x * (blockDim.x >> 6) + (threadIdx.x >> 6);
    int nw  = gridDim.x * (blockDim.x >> 6);
    float bsx = 0.f, bsy = 0.f, bsz = 0.f, bsw = 0.f;
    float bqx = 0.f, bqy = 0.f, bqz = 0.f, bqw = 0.f;
    for (int i = wid; i < n; i += nw) {
        int beg = off[i], end = off[i + 1];
        float4 xrv = xr4[(size_t)i * 16 + c16];
        float mmax = NINF, denom = 0.f;
        float ax = 0.f, ay = 0.f, az = 0.f, aw = 0.f;
        float ex = 0.f, ey = 0.f, ez = 0.f, ew = 0.f;
        if (beg < end) {
            // prologue: pack @ beg
            int rem = end - beg;
            int actc = (g < rem);
            int p = beg + (actc ? g : 0);
            int s0 = srcs[p];
            size_t q = 4 * (size_t)p;
            float4 e0 = eas4[q], e1 = eas4[q + 1], e2 = eas4[q + 2], e3 = eas4[q + 3];
            float4 X = xl4[(size_t)s0 * 16 + c16];
            for (int pos = beg; pos < end; pos += 4) {
                int posn = pos + 4;
                int remn = end - posn;
                int actn = (remn > 0) && (g < remn);
                int pn = (remn > 0) ? posn + (actn ? g : 0) : pos;
                int sn = srcs[pn];                      // issue next srcs
                size_t qn = 4 * (size_t)pn;             // issue next ea (independent)
                float4 ne0 = eas4[qn],     ne1 = eas4[qn + 1];
                float4 ne2 = eas4[qn + 2], ne3 = eas4[qn + 3];
                // eev for current pack (covers sn latency)
                float eex = EEV(x), eey = EEV(y), eez = EEV(z), eew = EEV(w);
                // next xl gather (sn arrived during eev)
                float4 xn = xl4[(size_t)sn * 16 + c16];
                float mk = actc ? 1.f : 0.f;
                ex += mk * eex; ey += mk * eey; ez += mk * eez; ew += mk * eew;
                float mx = X.x + xrv.x + eex;
                float my = X.y + xrv.y + eey;
                float mz = X.z + xrv.z + eez;
                float mw = X.w + xrv.w + eew;
                float p0 = fmaxf(mx, NEG * mx) * av.x
                         + fmaxf(my, NEG * my) * av.y
                         + fmaxf(mz, NEG * mz) * av.z
                         + fmaxf(mw, NEG * mw) * av.w;
                #pragma unroll
                for (int o = 1; o <= 8; o <<= 1) p0 += __shfl_xor(p0, o, 64);
                float t = actc ? p0 : NINF;
                float nm = fmaxf(mmax, t);
                float scal = (mmax == NINF) ? 0.f : __expf(mmax - nm);
                float ev = actc ? __expf(t - nm) : 0.f;
                denom = denom * scal + ev;
                ax = ax * scal + ev * X.x;
                ay = ay * scal + ev * X.y;
                az = az * scal + ev * X.z;
                aw = aw * scal + ev * X.w;
                mmax = nm;
                e0 = ne0; e1 = ne1; e2 = ne2; e3 = ne3; X = xn; actc = actn;
            }
        }
        // merge 4 per-group partials (m, l, acc, eevsum)
        #pragma unroll
        for (int o = 16; o <= 32; o <<= 1) {
            float om = __shfl_xor(mmax, o, 64);
            float od = __shfl_xor(denom, o, 64);
            float oax = __shfl_xor(ax, o, 64);
            float oay = __shfl_xor(ay, o, 64);
            float oaz = __shfl_xor(az, o, 64);
            float oaw = __shfl_xor(aw, o, 64);
            float oex = __shfl_xor(ex, o, 64);
            float oey = __shfl_xor(ey, o, 64);
            float oez = __shfl_xor(ez, o, 64);
            float oew = __shfl_xor(ew, o, 64);
            float nm = fmaxf(mmax, om);
            float s1 = (mmax == NINF) ? 0.f : __expf(mmax - nm);
            float s2 = (om == NINF) ? 0.f : __expf(om - nm);
            denom = denom * s1 + od * s2;
            ax = ax * s1 + oax * s2; ay = ay * s1 + oay * s2;
            az = az * s1 + oaz * s2; aw = aw * s1 + oaw * s2;
            ex += oex; ey += oey; ez += oez; ew += oew;
            mmax = nm;
        }
        // self-loop (loop_attr@We == mean of incoming eev; 0 if deg==0)
        int deg = end - beg;
        float inv = (deg > 0) ? 1.f / (float)deg : 0.f;
        float4 xli = xl4[(size_t)i * 16 + c16];
        float mx = xli.x + xrv.x + ex * inv;
        float my = xli.y + xrv.y + ey * inv;
        float mz = xli.z + xrv.z + ez * inv;
        float mw = xli.w + xrv.w + ew * inv;
        float p0 = fmaxf(mx, NEG * mx) * av.x
                 + fmaxf(my, NEG * my) * av.y
                 + fmaxf(mz, NEG * mz) * av.z
                 + fmaxf(mw, NEG * mw) * av.w;
        #pragma unroll
        for (int o = 1; o <= 8; o <<= 1) p0 += __shfl_xor(p0, o, 64);
        float nm = fmaxf(mmax, p0);
        float scal = (mmax == NINF) ? 0.f : __expf(mmax - nm);
        float ev = __expf(p0 - nm);
        denom = denom * scal + ev;
        ax = ax * scal + ev * xli.x;
        ay = ay * scal + ev * xli.y;
        az = az * scal + ev * xli.z;
        aw = aw * scal + ev * xli.w;
        float invd = 1.f / denom;
        float4 b4 = bias4[c16];
        float ox = ax * invd + b4.x;
        float oy = ay * invd + b4.y;
        float oz = az * invd + b4.z;
        float ow = aw * invd + b4.w;
        if (do_elu) {
            ox = (ox > 0.f) ? ox : expm1f(ox);
            oy = (oy > 0.f) ? oy : expm1f(oy);
            oz = (oz > 0.f) ? oz : expm1f(oz);
            ow = (ow > 0.f) ? ow : expm1f(ow);
        }
        if (g == 0) {
            float4 o4; o4.x = ox; o4.y = oy; o4.z = oz; o4.w = ow;
            ((float4*)out)[(size_t)i * 16 + c16] = o4;
            if (stat) {
                bsx += ox; bsy += oy; bsz += oz; bsw += ow;
                bqx += ox * ox; bqy += oy * oy; bqz += oz * oz; bqw += ow * ow;
            }
        }
    }
    if (stat) {
        if (g == 0) {
            atomicAdd(&ls[c16 * 4 + 0], bsx);
            atomicAdd(&ls[c16 * 4 + 1], bsy);
            atomicAdd(&ls[c16 * 4 + 2], bsz);
            atomicAdd(&ls[c16 * 4 + 3], bsw);
            atomicAdd(&ls[64 + c16 * 4 + 0], bqx);
            atomicAdd(&ls[64 + c16 * 4 + 1], bqy);
            atomicAdd(&ls[64 + c16 * 4 + 2], bqz);
            atomicAdd(&ls[64 + c16 * 4 + 3], bqw);
        }
        __syncthreads();
        if (threadIdx.x < 128) atomicAdd(&stat[threadIdx.x], ls[threadIdx.x]);
    }
}

// ---------------- launch ----------------

extern "C" void kernel_launch(void* const* d_in, const int* in_sizes, int n_in,
                              void* d_out, int out_size, void* d_ws, size_t ws_size,
                              hipStream_t stream) {
    const float* x     = (const float*)d_in[0];
    const int*   ei    = (const int*)d_in[1];
    const float* ea    = (const float*)d_in[2];
    const float* Wl    = (const float*)d_in[3];
    const float* Wr    = (const float*)d_in[4];
    const float* We    = (const float*)d_in[5];
    const float* att   = (const float*)d_in[6];
    const float* bias  = (const float*)d_in[7];
    const float* gamma = (const float*)d_in[8];
    const float* beta  = (const float*)d_in[9];
    float* out = (float*)d_out;

    int n = in_sizes[0] / D;
    int e = in_sizes[1] / 2;
    const int* src = ei;
    const int* dst = ei + e;
    int nb = (n + 1023) / 1024;

    float* xl   = (float*)d_ws;
    float* xr   = xl + (size_t)n * D;
    float* hbuf = xr + (size_t)n * D;
    float* stat = hbuf + (size_t)n * D;        // [2][128]: raw {sum,sq} per BN
    float* eas  = stat + 256;                   // [e][16] pre-sorted edge_attr
    int* cnt  = (int*)(eas + (size_t)e * ED);
    int* fill = cnt + n;                        // adjacent to cnt: one memset
    int* off  = fill + n;
    int* bsum = off + n + 1;
    int* srcs = bsum + 256;

    hipMemsetAsync(cnt, 0, (size_t)(2 * n) * sizeof(int), stream);
    k_count<<<(e + 255) / 256, 256, 0, stream>>>(dst, cnt, stat, e);
    k_scan1<<<nb, 1024, 0, stream>>>(cnt, off, bsum, n);
    k_scan2<<<1, 64, 0, stream>>>(bsum, nb);
    k_scan3<<<(n + 255) / 256, 256, 0, stream>>>(off, bsum, n);
    k_scatter<<<(e + 255) / 256, 256, 0, stream>>>(src, dst, off, fill, srcs,
                                                   (float4*)eas, (const float4*)ea, e);

    const int gemm_grid = 512;
    const int gat_grid  = 2048;

    // layer 0: conv -> ELU (in gat) -> BN0 stats (epilogue); BN0 apply folded into gemm1
    k_gemm<<<gemm_grid, 256, 0, stream>>>(x, Wl, Wr, xl, xr, stat, gamma, beta, 0, n);
    k_gat<<<gat_grid, 256, 0, stream>>>((const float4*)xl, (const float4*)xr,
                                        (const float4*)eas, srcs, off,
                                        (const float4*)We, (const float4*)att,
                                        (const float4*)bias, hbuf, stat, n, 1);
    // layer 1: conv (BN0 folded) -> BN1 stats (epilogue); BN1+ELU folded into gemm2
    k_gemm<<<gemm_grid, 256, 0, stream>>>(hbuf, Wl + D * D, Wr + D * D, xl, xr,
                                          stat, gamma, beta, 1, n);
    k_gat<<<gat_grid, 256, 0, stream>>>((const float4*)xl, (const float4*)xr,
                                        (const float4*)eas, srcs, off,
                                        (const float4*)(We + ED * D), (const float4*)(att + D),
                                        (const float4*)(bias + D), hbuf, stat + 128, n, 0);
    // layer 2: conv (BN1+ELU folded) -> out
    k_gemm<<<gemm_grid, 256, 0, stream>>>(hbuf, Wl + 2 * D * D, Wr + 2 * D * D, xl, xr,
                                          stat + 128, gamma + D, beta + D, 2, n);
    k_gat<<<gat_grid, 256, 0, stream>>>((const float4*)xl, (const float4*)xr,
                                        (const float4*)eas, srcs, off,
                                        (const float4*)(We + 2 * ED * D), (const float4*)(att + 2 * D),
                                        (const float4*)(bias + 2 * D), out, (float*)nullptr, n, 0);
}